// Round 10
// baseline (2101.288 us; speedup 1.0000x reference)
//
#include <hip/hip_runtime.h>

#define EPSN 1e-6f

typedef __attribute__((ext_vector_type(4))) float f32x4;
typedef __attribute__((ext_vector_type(8))) __bf16 bf16x8;
typedef __attribute__((ext_vector_type(8))) unsigned short us8;

__device__ __forceinline__ void async16(const void* g, void* l) {
  __builtin_amdgcn_global_load_lds(
      (const __attribute__((address_space(1))) unsigned int*)g,
      (__attribute__((address_space(3))) unsigned int*)l, 16, 0, 0);
}

// 3-level bf16 split: v ~= hi + mid + lo to ~2^-26 rel
__device__ __forceinline__ void split3(float v, unsigned short& h, unsigned short& m,
                                       unsigned short& l) {
  __bf16 a = (__bf16)v;  float fa = (float)a;
  __bf16 b = (__bf16)(v - fa); float fb = (float)b;
  __bf16 c = (__bf16)(v - fa - fb);
  h = __builtin_bit_cast(unsigned short, a);
  m = __builtin_bit_cast(unsigned short, b);
  l = __builtin_bit_cast(unsigned short, c);
}

// ---- transpose: out[c][r] = in[r][c], in [R][C] fp32 (for conv1 A-side)
__global__ void kTx(const float* __restrict__ in, float* __restrict__ out, int R, int C) {
  __shared__ float t[32][33];
  int r0 = blockIdx.x * 32, c0 = blockIdx.y * 32;
  int tx = threadIdx.x, ty = threadIdx.y;  // (32,8)
#pragma unroll
  for (int j = 0; j < 4; ++j)
    t[ty + j * 8][tx] = in[(size_t)(r0 + ty + j * 8) * C + c0 + tx];
  __syncthreads();
#pragma unroll
  for (int j = 0; j < 4; ++j)
    out[(size_t)(c0 + ty + j * 8) * R + r0 + tx] = t[tx][ty + j * 8];
}

// ==== fp32 vector GEMM (proven) — conv1/conv2 only ====
__global__ __launch_bounds__(256, 2) void kgf(
    const float* __restrict__ A0, int lda0, const float* __restrict__ A1, int lda1,
    const float* __restrict__ B0, const float* __restrict__ B1, int ldb,
    int splitK, int N, int M, int kchunk, float* __restrict__ outp) {
  __shared__ float lsA[2][16 * 128];
  __shared__ float lsB[2][16 * 128];
  const int tid = threadIdx.x;
  const int n0 = blockIdx.x * 128, m0 = blockIdx.y * 128;
  const int kbase = blockIdx.z * kchunk;
  const float* A; int lda; const float* B; int koff;
  if (kbase < splitK) { A = A0; lda = lda0; B = B0; koff = kbase; }
  else                { A = A1; lda = lda1; B = B1; koff = kbase - splitK; }
  const int nt = kchunk >> 4;
  const float* asrc[2]; const float* bsrc[2];
#pragma unroll
  for (int j = 0; j < 2; ++j) {
    int idx = j * 256 + tid;
    int r = idx >> 5, c4 = (idx & 31) * 4;
    asrc[j] = A + (size_t)(koff + r) * lda + m0 + c4;
    bsrc[j] = B + (size_t)(koff + r) * ldb + n0 + c4;
  }
  const size_t astep = (size_t)16 * lda, bstep = (size_t)16 * ldb;
  const int wbase = (tid & ~63) * 16;
  auto STAGE = [&](int buf) {
#pragma unroll
    for (int j = 0; j < 2; ++j) {
      async16(asrc[j], (char*)&lsA[buf][0] + j * 4096 + wbase);
      async16(bsrc[j], (char*)&lsB[buf][0] + j * 4096 + wbase);
      asrc[j] += astep; bsrc[j] += bstep;
    }
  };
  const int mg = tid >> 4, ng = tid & 15;
  f32x4 acc[8][2];
#pragma unroll
  for (int i = 0; i < 8; ++i) { acc[i][0] = (f32x4){0,0,0,0}; acc[i][1] = (f32x4){0,0,0,0}; }
  STAGE(0);
  __syncthreads();
  int buf = 0;
  for (int t = 0; t < nt; ++t) {
    if (t + 1 < nt) STAGE(buf ^ 1);
#pragma unroll
    for (int k = 0; k < 16; ++k) {
      f32x4 a0 = *(const f32x4*)&lsA[buf][k * 128 + mg * 8];
      f32x4 a1 = *(const f32x4*)&lsA[buf][k * 128 + mg * 8 + 4];
      f32x4 b0 = *(const f32x4*)&lsB[buf][k * 128 + ng * 4];
      f32x4 b1 = *(const f32x4*)&lsB[buf][k * 128 + ng * 4 + 64];
#pragma unroll
      for (int i = 0; i < 8; ++i) {
        float av = (i < 4) ? a0[i] : a1[i - 4];
        acc[i][0] += av * b0; acc[i][1] += av * b1;
      }
    }
    __syncthreads();
    buf ^= 1;
  }
  float* o = outp + ((size_t)blockIdx.z * M + m0 + mg * 8) * N + n0;
#pragma unroll
  for (int i = 0; i < 8; ++i) {
    *(f32x4*)&o[(size_t)i * N + ng * 4] = acc[i][0];
    *(f32x4*)&o[(size_t)i * N + ng * 4 + 64] = acc[i][1];
  }
}

// ==== MFMA emulated-fp32 GEMM (6-term 3-way bf16 split) ====
// BM=BN=256, BK=32, 512 threads / 8 waves, wave tile 64x128, 16x16x32 MFMA.
// A: pre-split bf16 triples [m][2048] row-major; kbase<2048 -> (Ah0..)/B0 else (Ah1..)/B1.
// B fp32 [k][8192]. out[bz][m][n], Mrows rows per partial. kchunk must not straddle 2048.
__global__ __launch_bounds__(512, 2) void kgm(
    const unsigned short* __restrict__ Ah0, const unsigned short* __restrict__ Am0,
    const unsigned short* __restrict__ Al0,
    const unsigned short* __restrict__ Ah1, const unsigned short* __restrict__ Am1,
    const unsigned short* __restrict__ Al1,
    const float* __restrict__ B0, const float* __restrict__ B1,
    int Mrows, int kchunk, float* __restrict__ outp) {
  __shared__ unsigned short lsA[3 * 256 * 32];     // [split][m][32k], slot XOR-swz; 48KB
  __shared__ unsigned short lsB[3 * 4 * 256 * 8];  // [split][kq][n][8k], linear; 48KB
  const int tid = threadIdx.x, lane = tid & 63, wid = tid >> 6;
  const int n0 = blockIdx.x * 256, m0 = blockIdx.y * 256;
  const int kbase = blockIdx.z * kchunk;

  const unsigned short *Ah, *Am, *Al; const float* B; int koff;
  if (kbase < 2048) { Ah = Ah0; Am = Am0; Al = Al0; B = B0; koff = kbase; }
  else              { Ah = Ah1; Am = Am1; Al = Al1; B = B1; koff = kbase - 2048; }
  const int nt = kchunk >> 5;

  // --- A: 3072 16B-chunks, 6/thread, reg-staged (T14). idx=j*512+tid ->
  // split=idx>>10, row=(idx&1023)>>2, slot=idx&3; write slot XOR-swizzled.
  const unsigned short* asrc[6];
  int awoff[6];
#pragma unroll
  for (int j = 0; j < 6; ++j) {
    int idx = j * 512 + tid;
    int s = idx >> 10, rem = idx & 1023, row = rem >> 2, slot = rem & 3;
    const unsigned short* base = (s == 0) ? Ah : ((s == 1) ? Am : Al);
    asrc[j] = base + (size_t)(m0 + row) * 2048 + koff + slot * 8;
    awoff[j] = s * 8192 + row * 32 + ((slot ^ ((row >> 1) & 3)) << 3);
  }
  us8 ar[6];
  auto LOADA = [&]() {
#pragma unroll
    for (int j = 0; j < 6; ++j) { ar[j] = *(const us8*)asrc[j]; asrc[j] += 32; }
  };
  auto WRITEA = [&]() {
#pragma unroll
    for (int j = 0; j < 6; ++j) *(us8*)&lsA[awoff[j]] = ar[j];
  };

  // --- B: thread owns k rows kq*8..+7 (kq=tid>>7), n in {nn, nn+128} (nn=tid&127).
  const int kq = tid >> 7, nn = tid & 127;
  const float* bptr = B + (size_t)(koff + kq * 8) * 8192 + n0 + nn;
  const int bo0 = kq * 2048 + nn * 8;
  const int bo1 = kq * 2048 + (nn + 128) * 8;
  float bwa[8], bwb[8];
  us8 bs[6];
  auto LOADB = [&]() {
#pragma unroll
    for (int r = 0; r < 8; ++r) {
      bwa[r] = bptr[(size_t)r * 8192];
      bwb[r] = bptr[(size_t)r * 8192 + 128];
    }
    bptr += (size_t)32 * 8192;
  };
  auto SPLITB = [&]() {
#pragma unroll
    for (int r = 0; r < 8; ++r) {
      unsigned short h, m, l;
      split3(bwa[r], h, m, l);
      bs[0][r] = h; bs[1][r] = m; bs[2][r] = l;
      split3(bwb[r], h, m, l);
      bs[3][r] = h; bs[4][r] = m; bs[5][r] = l;
    }
  };
  auto WRITEB = [&]() {
    *(us8*)&lsB[bo0] = bs[0];
    *(us8*)&lsB[8192 + bo0] = bs[1];
    *(us8*)&lsB[16384 + bo0] = bs[2];
    *(us8*)&lsB[bo1] = bs[3];
    *(us8*)&lsB[8192 + bo1] = bs[4];
    *(us8*)&lsB[16384 + bo1] = bs[5];
  };

  const int c0 = lane >> 4, l15 = lane & 15;
  const int wm = wid >> 1, wn = wid & 1;  // wave tile: m 64-block wm, n 128-block wn
  f32x4 acc[4][8];
#pragma unroll
  for (int i = 0; i < 4; ++i)
#pragma unroll
    for (int j = 0; j < 8; ++j) acc[i][j] = (f32x4){0, 0, 0, 0};

  LOADA();
  LOADB();
  SPLITB();
  for (int t = 0; t < nt; ++t) {
    __syncthreads();  // [1] prev compute done reading LDS
    WRITEA();
    WRITEB();
    __syncthreads();  // [2] tiles ready
    bool more = (t + 1 < nt);
    if (more) { LOADA(); LOADB(); }  // global latency hides under MFMA
    bf16x8 a[4][3];
#pragma unroll
    for (int mf = 0; mf < 4; ++mf) {
      int m = wm * 64 + mf * 16 + l15;
      int ro = m * 32 + ((c0 ^ ((m >> 1) & 3)) << 3);
      a[mf][0] = *(const bf16x8*)&lsA[ro];
      a[mf][1] = *(const bf16x8*)&lsA[8192 + ro];
      a[mf][2] = *(const bf16x8*)&lsA[16384 + ro];
    }
#pragma unroll
    for (int nf = 0; nf < 8; ++nf) {
      int ro = c0 * 2048 + (wn * 128 + nf * 16 + l15) * 8;
      bf16x8 b0 = *(const bf16x8*)&lsB[ro];
      bf16x8 b1 = *(const bf16x8*)&lsB[8192 + ro];
      bf16x8 b2 = *(const bf16x8*)&lsB[16384 + ro];
#pragma unroll
      for (int mf = 0; mf < 4; ++mf) {
        acc[mf][nf] = __builtin_amdgcn_mfma_f32_16x16x32_bf16(a[mf][0], b0, acc[mf][nf], 0, 0, 0);
        acc[mf][nf] = __builtin_amdgcn_mfma_f32_16x16x32_bf16(a[mf][1], b0, acc[mf][nf], 0, 0, 0);
        acc[mf][nf] = __builtin_amdgcn_mfma_f32_16x16x32_bf16(a[mf][2], b0, acc[mf][nf], 0, 0, 0);
        acc[mf][nf] = __builtin_amdgcn_mfma_f32_16x16x32_bf16(a[mf][0], b1, acc[mf][nf], 0, 0, 0);
        acc[mf][nf] = __builtin_amdgcn_mfma_f32_16x16x32_bf16(a[mf][1], b1, acc[mf][nf], 0, 0, 0);
        acc[mf][nf] = __builtin_amdgcn_mfma_f32_16x16x32_bf16(a[mf][0], b2, acc[mf][nf], 0, 0, 0);
      }
    }
    if (more) SPLITB();  // VALU; overlaps MFMA tail
  }

  // C/D: col = lane&15, row = (lane>>4)*4 + r  [m89-verified]
#pragma unroll
  for (int mf = 0; mf < 4; ++mf)
#pragma unroll
    for (int nf = 0; nf < 8; ++nf)
#pragma unroll
      for (int r = 0; r < 4; ++r) {
        int m = m0 + wm * 64 + mf * 16 + c0 * 4 + r;
        int n = n0 + wn * 128 + nf * 16 + l15;
        outp[((size_t)blockIdx.z * Mrows + m) * 8192 + n] = acc[mf][nf][r];
      }
}

// ---- gates: sums 8 z-partials (+ up to 2 zextra), all-tanh; writes h split triple
// (row-major [256][2048]) + optional ydecT fp32 gather for conv2.
__global__ void k_gates(const float* __restrict__ zpart,
                        const float* __restrict__ zx0, const float* __restrict__ zx1,
                        const float* __restrict__ bias, float* __restrict__ c,
                        unsigned short* __restrict__ Hh, unsigned short* __restrict__ Hm,
                        unsigned short* __restrict__ Hl,
                        float* __restrict__ ydecT, int s) {
  int i = blockIdx.x * 256 + threadIdx.x;
  int b = i >> 11, u = i & 2047;
  float g4[4];
#pragma unroll
  for (int gi = 0; gi < 4; ++gi) {
    int n = u + gi * 2048;
    float v = bias[n];
#pragma unroll
    for (int p = 0; p < 8; ++p) v += zpart[((size_t)p * 256 + b) * 8192 + n];
    if (zx0) v += zx0[(size_t)b * 8192 + n];
    if (zx1) v += zx1[(size_t)b * 8192 + n];
    g4[gi] = tanhf(v);
  }
  float cn = g4[1] * c[i] + g4[0] * g4[2];
  c[i] = cn;
  float h = g4[3] * tanhf(cn);
  unsigned short hh, hm, hl;
  split3(h, hh, hm, hl);
  Hh[i] = hh; Hm[i] = hm; Hl[i] = hl;
  if (ydecT) ydecT[(size_t)(u & 511) * 4096 + b * 16 + ((u >> 9) << 2) + s] = h;
}

// ---- IN+lrelu after conv1 (sums 4 kgf partials), writes steps split triple
// rows m = w*256+b, cols k = hh*512+d  ([1024][2048] row-major)
__global__ void k_inorm1(const float* __restrict__ part, const float* __restrict__ gamma,
                         const float* __restrict__ beta,
                         unsigned short* __restrict__ Sh, unsigned short* __restrict__ Sm,
                         unsigned short* __restrict__ Sl) {
  int d = blockIdx.y * 256 + threadIdx.x;  // 0..511
  int b = blockIdx.x;
  float v[16], s = 0.f, s2 = 0.f;
#pragma unroll
  for (int p = 0; p < 16; ++p) {
    float xv = 0.f;
#pragma unroll
    for (int q = 0; q < 4; ++q) xv += part[((size_t)q * 4096 + b * 16 + p) * 512 + d];
    v[p] = xv; s += xv; s2 += xv * xv;
  }
  float mean = s * (1.f / 16.f);
  float var = s2 * (1.f / 16.f) - mean * mean;
  float sc = gamma[d] * rsqrtf(var + EPSN);
  float bt = beta[d];
#pragma unroll
  for (int p = 0; p < 16; ++p) {
    int hh = p >> 2, w = p & 3;
    float xn = (v[p] - mean) * sc + bt;
    xn = xn >= 0.f ? xn : 0.2f * xn;
    size_t a = (size_t)(w * 256 + b) * 2048 + hh * 512 + d;
    unsigned short th, tm, tl;
    split3(xn, th, tm, tl);
    Sh[a] = th; Sm[a] = tm; Sl[a] = tl;
  }
}

// ---- IN+lrelu after conv2 (sums 2 kgf partials), writes final out [B,4,4,1024]
__global__ void k_inorm2(const float* __restrict__ part, const float* __restrict__ gamma,
                         const float* __restrict__ beta, float* __restrict__ out) {
  int o = blockIdx.y * 256 + threadIdx.x;  // 0..1023
  int b = blockIdx.x;
  float v[16], s = 0.f, s2 = 0.f;
#pragma unroll
  for (int p = 0; p < 16; ++p) {
    float xv = part[((size_t)(b * 16 + p)) * 1024 + o] +
               part[((size_t)(4096 + b * 16 + p)) * 1024 + o];
    v[p] = xv; s += xv; s2 += xv * xv;
  }
  float mean = s * (1.f / 16.f);
  float var = s2 * (1.f / 16.f) - mean * mean;
  float sc = gamma[o] * rsqrtf(var + EPSN);
  float bt = beta[o];
#pragma unroll
  for (int p = 0; p < 16; ++p) {
    float xn = (v[p] - mean) * sc + bt;
    xn = xn >= 0.f ? xn : 0.2f * xn;
    out[((size_t)(b * 16 + p)) * 1024 + o] = xn;
  }
}

extern "C" void kernel_launch(void* const* d_in, const int* in_sizes, int n_in,
                              void* d_out, int out_size, void* d_ws, size_t ws_size,
                              hipStream_t stream) {
  (void)in_sizes; (void)n_in; (void)out_size;
  const float* x     = (const float*)d_in[0];
  const float* w1    = (const float*)d_in[1];
  const float* g1    = (const float*)d_in[2];
  const float* b1    = (const float*)d_in[3];
  const float* enc_k = (const float*)d_in[4];
  const float* enc_r = (const float*)d_in[5];
  const float* enc_b = (const float*)d_in[6];
  const float* dec_k = (const float*)d_in[7];
  const float* dec_r = (const float*)d_in[8];
  const float* dec_b = (const float*)d_in[9];
  const float* w2    = (const float*)d_in[10];
  const float* g2    = (const float*)d_in[11];
  const float* b2    = (const float*)d_in[12];
  float* out = (float*)d_out;

  if (ws_size < 176160768ULL) return;  // 168 MiB known-good bound (r1 ran)

  // Manual layout, 166 MiB total:
  //  [0,64Mi)    zpart: 8 cell partials [256][8192] f32; also conv1 (4x) / alias-safe
  //  [64,128Mi)  ZX: 2 partials [1024][8192] f32; reused by nothing until enc done
  //  [128,144Mi) xT [1024][4096] f32 (dead after conv1) -> ydecT(8Mi)+h1s(3Mi)+h2s(3Mi)
  //  [144,156Mi) st3: steps split triple [3][1024][2048] bf16
  //  [156,159Mi) y0s  [159,162Mi) y1s  [162,164Mi) c1  [164,166Mi) c2
  char* base = (char*)d_ws;
  float* zpart = (float*)base;
  float* ZX    = (float*)(base + (64ull << 20));
  char*  xreg  = base + (128ull << 20);
  float* xT    = (float*)xreg;
  float* ydecT = (float*)xreg;
  unsigned short* h1s = (unsigned short*)(xreg + (8ull << 20));
  unsigned short* h2s = (unsigned short*)(xreg + (11ull << 20));
  unsigned short* st3 = (unsigned short*)(base + (144ull << 20));
  unsigned short* y0s = (unsigned short*)(base + (156ull << 20));
  unsigned short* y1s = (unsigned short*)(base + (159ull << 20));
  float* c1 = (float*)(base + (162ull << 20));
  float* c2 = (float*)(base + (164ull << 20));

  const size_t SP = 1024ull * 2048;   // steps split stride
  const size_t HP = 256ull * 2048;    // h split stride
  unsigned short *sth = st3, *stm = st3 + SP, *stl = st3 + 2 * SP;
  unsigned short *h1h = h1s, *h1m = h1s + HP, *h1l = h1s + 2 * HP;
  unsigned short *h2h = h2s, *h2m = h2s + HP, *h2l = h2s + 2 * HP;
  unsigned short* ys[2] = {y0s, y1s};

  // conv1 (fp32 path) — uses xT region, so h1s/h2s memsets come AFTER
  kTx<<<dim3(128, 32), dim3(32, 8), 0, stream>>>(x, xT, 4096, 1024);
  kgf<<<dim3(4, 32, 4), 256, 0, stream>>>(xT, 4096, xT, 4096, w1, w1, 512,
                                          1024, 512, 4096, 256, zpart);
  k_inorm1<<<dim3(256, 2), 256, 0, stream>>>(zpart, g1, b1, sth, stm, stl);

  hipMemsetAsync(h1s, 0, 3 * HP * 2, stream);
  hipMemsetAsync(h2s, 0, 3 * HP * 2, stream);
  hipMemsetAsync(c1, 0, HP * 4, stream);
  hipMemsetAsync(c2, 0, HP * 4, stream);

  // ZX = steps @ enc_k (all 4 timesteps): [1024 x 2048] @ [2048][8192], 2 partials
  kgm<<<dim3(32, 4, 2), 512, 0, stream>>>(sth, stm, stl, sth, stm, stl,
                                          enc_k, enc_k, 1024, 1024, ZX);

  // encoder: 4 steps x 2 shared-weight layers
  for (int t = 0; t < 4; ++t) {
    kgm<<<dim3(32, 1, 8), 512, 0, stream>>>(h1h, h1m, h1l, h1h, h1m, h1l,
                                            enc_r, enc_r, 256, 256, zpart);
    k_gates<<<2048, 256, 0, stream>>>(zpart, ZX + (size_t)t * 256 * 8192,
                                      ZX + (size_t)(1024 + t * 256) * 8192, enc_b, c1,
                                      h1h, h1m, h1l, nullptr, 0);
    kgm<<<dim3(32, 1, 8), 512, 0, stream>>>(h1h, h1m, h1l, h2h, h2m, h2l,
                                            enc_k, enc_r, 256, 512, zpart);
    k_gates<<<2048, 256, 0, stream>>>(zpart, nullptr, nullptr, enc_b, c2,
                                      h2h, h2m, h2l, nullptr, 0);
  }
  // decoder
  for (int s = 0; s < 4; ++s) {
    const unsigned short *xh, *xm, *xl, *ph, *pm, *pl;
    if (s == 0) {
      xh = sth + 768 * 2048; xm = stm + 768 * 2048; xl = stl + 768 * 2048;
      ph = h2h; pm = h2m; pl = h2l;
    } else {
      unsigned short* pr = ys[(s - 1) & 1];
      xh = pr; xm = pr + HP; xl = pr + 2 * HP;
      ph = pr; pm = pr + HP; pl = pr + 2 * HP;
    }
    kgm<<<dim3(32, 1, 8), 512, 0, stream>>>(xh, xm, xl, h1h, h1m, h1l,
                                            dec_k, dec_r, 256, 512, zpart);
    k_gates<<<2048, 256, 0, stream>>>(zpart, nullptr, nullptr, dec_b, c1,
                                      h1h, h1m, h1l, nullptr, 0);
    kgm<<<dim3(32, 1, 8), 512, 0, stream>>>(h1h, h1m, h1l, ph, pm, pl,
                                            dec_k, dec_r, 256, 512, zpart);
    unsigned short* cur = ys[s & 1];
    k_gates<<<2048, 256, 0, stream>>>(zpart, nullptr, nullptr, dec_b, c2,
                                      cur, cur + HP, cur + 2 * HP, ydecT, s);
  }

  // conv2 (fp32 path): gathered y [4096 x 512] @ w2 -> zpart[2][4096][1024]
  kgf<<<dim3(8, 32, 2), 256, 0, stream>>>(ydecT, 4096, ydecT, 4096, w2, w2, 1024,
                                          512, 1024, 4096, 256, zpart);
  k_inorm2<<<dim3(256, 4), 256, 0, stream>>>(zpart, g2, b2, out);
}

// Round 11
// 1732.578 us; speedup vs baseline: 1.2128x; 1.2128x over previous
//
#include <hip/hip_runtime.h>

#define EPSN 1e-6f

typedef __attribute__((ext_vector_type(4))) float f32x4;
typedef __attribute__((ext_vector_type(8))) __bf16 bf16x8;
typedef __attribute__((ext_vector_type(8))) unsigned short us8;

__device__ __forceinline__ void async16(const void* g, void* l) {
  __builtin_amdgcn_global_load_lds(
      (const __attribute__((address_space(1))) unsigned int*)g,
      (__attribute__((address_space(3))) unsigned int*)l, 16, 0, 0);
}

// 3-level bf16 split: v ~= hi + mid + lo to ~2^-26 rel
__device__ __forceinline__ void split3(float v, unsigned short& h, unsigned short& m,
                                       unsigned short& l) {
  __bf16 a = (__bf16)v;  float fa = (float)a;
  __bf16 b = (__bf16)(v - fa); float fb = (float)b;
  __bf16 c = (__bf16)(v - fa - fb);
  h = __builtin_bit_cast(unsigned short, a);
  m = __builtin_bit_cast(unsigned short, b);
  l = __builtin_bit_cast(unsigned short, c);
}

// ---- transpose: out[c][r] = in[r][c], in [R][C] fp32 (for conv1 A-side)
__global__ void kTx(const float* __restrict__ in, float* __restrict__ out, int R, int C) {
  __shared__ float t[32][33];
  int r0 = blockIdx.x * 32, c0 = blockIdx.y * 32;
  int tx = threadIdx.x, ty = threadIdx.y;  // (32,8)
#pragma unroll
  for (int j = 0; j < 4; ++j)
    t[ty + j * 8][tx] = in[(size_t)(r0 + ty + j * 8) * C + c0 + tx];
  __syncthreads();
#pragma unroll
  for (int j = 0; j < 4; ++j)
    out[(size_t)(c0 + ty + j * 8) * R + r0 + tx] = t[tx][ty + j * 8];
}

// ==== fp32 vector GEMM (proven) — conv1/conv2 only ====
__global__ __launch_bounds__(256, 2) void kgf(
    const float* __restrict__ A0, int lda0, const float* __restrict__ A1, int lda1,
    const float* __restrict__ B0, const float* __restrict__ B1, int ldb,
    int splitK, int N, int M, int kchunk, float* __restrict__ outp) {
  __shared__ float lsA[2][16 * 128];
  __shared__ float lsB[2][16 * 128];
  const int tid = threadIdx.x;
  const int n0 = blockIdx.x * 128, m0 = blockIdx.y * 128;
  const int kbase = blockIdx.z * kchunk;
  const float* A; int lda; const float* B; int koff;
  if (kbase < splitK) { A = A0; lda = lda0; B = B0; koff = kbase; }
  else                { A = A1; lda = lda1; B = B1; koff = kbase - splitK; }
  const int nt = kchunk >> 4;
  const float* asrc[2]; const float* bsrc[2];
#pragma unroll
  for (int j = 0; j < 2; ++j) {
    int idx = j * 256 + tid;
    int r = idx >> 5, c4 = (idx & 31) * 4;
    asrc[j] = A + (size_t)(koff + r) * lda + m0 + c4;
    bsrc[j] = B + (size_t)(koff + r) * ldb + n0 + c4;
  }
  const size_t astep = (size_t)16 * lda, bstep = (size_t)16 * ldb;
  const int wbase = (tid & ~63) * 16;
  auto STAGE = [&](int buf) {
#pragma unroll
    for (int j = 0; j < 2; ++j) {
      async16(asrc[j], (char*)&lsA[buf][0] + j * 4096 + wbase);
      async16(bsrc[j], (char*)&lsB[buf][0] + j * 4096 + wbase);
      asrc[j] += astep; bsrc[j] += bstep;
    }
  };
  const int mg = tid >> 4, ng = tid & 15;
  f32x4 acc[8][2];
#pragma unroll
  for (int i = 0; i < 8; ++i) { acc[i][0] = (f32x4){0,0,0,0}; acc[i][1] = (f32x4){0,0,0,0}; }
  STAGE(0);
  __syncthreads();
  int buf = 0;
  for (int t = 0; t < nt; ++t) {
    if (t + 1 < nt) STAGE(buf ^ 1);
#pragma unroll
    for (int k = 0; k < 16; ++k) {
      f32x4 a0 = *(const f32x4*)&lsA[buf][k * 128 + mg * 8];
      f32x4 a1 = *(const f32x4*)&lsA[buf][k * 128 + mg * 8 + 4];
      f32x4 b0 = *(const f32x4*)&lsB[buf][k * 128 + ng * 4];
      f32x4 b1 = *(const f32x4*)&lsB[buf][k * 128 + ng * 4 + 64];
#pragma unroll
      for (int i = 0; i < 8; ++i) {
        float av = (i < 4) ? a0[i] : a1[i - 4];
        acc[i][0] += av * b0; acc[i][1] += av * b1;
      }
    }
    __syncthreads();
    buf ^= 1;
  }
  float* o = outp + ((size_t)blockIdx.z * M + m0 + mg * 8) * N + n0;
#pragma unroll
  for (int i = 0; i < 8; ++i) {
    *(f32x4*)&o[(size_t)i * N + ng * 4] = acc[i][0];
    *(f32x4*)&o[(size_t)i * N + ng * 4 + 64] = acc[i][1];
  }
}

// ==== MFMA emulated-fp32 GEMM (6-term 3-way bf16 split) ====
// BM=BN=256, BK=32, 512 threads / 8 waves, wave tile 64x128, 16x16x32 MFMA.
// A: pre-split bf16 triples [m][2048] row-major; kbase<2048 -> (Ah0..)/B0 else (Ah1..)/B1.
// B fp32 [k][8192]. out[bz][m][n], Mrows rows per partial. kchunk must not straddle 2048.
// A staged via global_load_lds into DOUBLE-buffered lsA (src slot-XOR pre-swizzled,
// linear dest); issued after barrier [2], drained by next iter's barrier -> hidden
// under MFMA. B reg-loaded + split3 + conflict-free ds_write_b128 (single lsB).
__global__ __launch_bounds__(512, 1) void kgm(
    const unsigned short* __restrict__ Ah0, const unsigned short* __restrict__ Am0,
    const unsigned short* __restrict__ Al0,
    const unsigned short* __restrict__ Ah1, const unsigned short* __restrict__ Am1,
    const unsigned short* __restrict__ Al1,
    const float* __restrict__ B0, const float* __restrict__ B1,
    int Mrows, int kchunk, float* __restrict__ outp) {
  __shared__ unsigned short lsA[2][3 * 256 * 32];  // 2 x 48KB, [split][m][32k], slot-XOR swz
  __shared__ unsigned short lsB[3 * 4 * 256 * 8];  // 48KB, [split][kq][n][8k], linear
  const int tid = threadIdx.x, lane = tid & 63, wid = tid >> 6;
  const int n0 = blockIdx.x * 256, m0 = blockIdx.y * 256;
  const int kbase = blockIdx.z * kchunk;

  const unsigned short *Ah, *Am, *Al; const float* B; int koff;
  if (kbase < 2048) { Ah = Ah0; Am = Am0; Al = Al0; B = B0; koff = kbase; }
  else              { Ah = Ah1; Am = Am1; Al = Al1; B = B1; koff = kbase - 2048; }
  const int nt = kchunk >> 5;

  // --- A: 3072 16B-chunks, 6/thread. idx=j*512+tid -> split=idx>>10,
  // row=(idx&1023)>>2, slot=idx&3. Dest linear idx*16B (wave-uniform base + lane*16);
  // SOURCE pre-swizzled slot^((row>>1)&3); read applies the same XOR.
  const unsigned short* asrc[6];
  int adst[6];
#pragma unroll
  for (int j = 0; j < 6; ++j) {
    int idx = j * 512 + tid;
    int s = idx >> 10, rem = idx & 1023, row = rem >> 2, slot = idx & 3;
    const unsigned short* base = (s == 0) ? Ah : ((s == 1) ? Am : Al);
    asrc[j] = base + (size_t)(m0 + row) * 2048 + koff + ((slot ^ ((row >> 1) & 3)) << 3);
    adst[j] = (j * 512 + (tid & ~63)) * 16;  // wave-uniform byte base; HW adds lane*16
  }
  auto STAGEA = [&](int buf) {
#pragma unroll
    for (int j = 0; j < 6; ++j) {
      async16(asrc[j], (char*)&lsA[buf][0] + adst[j]);
      asrc[j] += 32;
    }
  };

  // --- B: thread owns k rows kq*8..+7 (kq=tid>>7), n in {nn, nn+128} (nn=tid&127).
  const int kq = tid >> 7, nn = tid & 127;
  const float* bptr = B + (size_t)(koff + kq * 8) * 8192 + n0 + nn;
  const int bo0 = kq * 2048 + nn * 8;
  const int bo1 = kq * 2048 + (nn + 128) * 8;
  float bwa[8], bwb[8];
  us8 bs[6];
  auto LOADB = [&]() {
#pragma unroll
    for (int r = 0; r < 8; ++r) {
      bwa[r] = bptr[(size_t)r * 8192];
      bwb[r] = bptr[(size_t)r * 8192 + 128];
    }
    bptr += (size_t)32 * 8192;
  };
  auto SPLITB = [&]() {
#pragma unroll
    for (int r = 0; r < 8; ++r) {
      unsigned short h, m, l;
      split3(bwa[r], h, m, l);
      bs[0][r] = h; bs[1][r] = m; bs[2][r] = l;
      split3(bwb[r], h, m, l);
      bs[3][r] = h; bs[4][r] = m; bs[5][r] = l;
    }
  };
  auto WRITEB = [&]() {
    *(us8*)&lsB[bo0] = bs[0];
    *(us8*)&lsB[8192 + bo0] = bs[1];
    *(us8*)&lsB[16384 + bo0] = bs[2];
    *(us8*)&lsB[bo1] = bs[3];
    *(us8*)&lsB[8192 + bo1] = bs[4];
    *(us8*)&lsB[16384 + bo1] = bs[5];
  };

  const int c0 = lane >> 4, l15 = lane & 15;
  const int wm = wid >> 1, wn = wid & 1;  // wave tile: m 64-block wm, n 128-block wn
  f32x4 acc[4][8];
#pragma unroll
  for (int i = 0; i < 4; ++i)
#pragma unroll
    for (int j = 0; j < 8; ++j) acc[i][j] = (f32x4){0, 0, 0, 0};

  STAGEA(0);
  LOADB();
  SPLITB();
  int abuf = 0;
  for (int t = 0; t < nt; ++t) {
    __syncthreads();  // [1] prev compute done (lsB + lsA[abuf^1] free)
    WRITEB();
    __syncthreads();  // [2] lsB ready; asyncA(t) drained (barrier implies vmcnt(0))
    bool more = (t + 1 < nt);
    if (more) {
      STAGEA(abuf ^ 1);  // A(t+1): DMA runs during compute, drained at next [1]/[2]
      LOADB();           // B(t+1) into regs; latency hidden under MFMA
    }
    bf16x8 a[4][3];
#pragma unroll
    for (int mf = 0; mf < 4; ++mf) {
      int m = wm * 64 + mf * 16 + l15;
      int ro = m * 32 + ((c0 ^ ((m >> 1) & 3)) << 3);
      a[mf][0] = *(const bf16x8*)&lsA[abuf][ro];
      a[mf][1] = *(const bf16x8*)&lsA[abuf][8192 + ro];
      a[mf][2] = *(const bf16x8*)&lsA[abuf][16384 + ro];
    }
#pragma unroll
    for (int nf = 0; nf < 8; ++nf) {
      int ro = c0 * 2048 + (wn * 128 + nf * 16 + l15) * 8;
      bf16x8 b0 = *(const bf16x8*)&lsB[ro];
      bf16x8 b1 = *(const bf16x8*)&lsB[8192 + ro];
      bf16x8 b2 = *(const bf16x8*)&lsB[16384 + ro];
#pragma unroll
      for (int mf = 0; mf < 4; ++mf) {
        acc[mf][nf] = __builtin_amdgcn_mfma_f32_16x16x32_bf16(a[mf][0], b0, acc[mf][nf], 0, 0, 0);
        acc[mf][nf] = __builtin_amdgcn_mfma_f32_16x16x32_bf16(a[mf][1], b0, acc[mf][nf], 0, 0, 0);
        acc[mf][nf] = __builtin_amdgcn_mfma_f32_16x16x32_bf16(a[mf][2], b0, acc[mf][nf], 0, 0, 0);
        acc[mf][nf] = __builtin_amdgcn_mfma_f32_16x16x32_bf16(a[mf][0], b1, acc[mf][nf], 0, 0, 0);
        acc[mf][nf] = __builtin_amdgcn_mfma_f32_16x16x32_bf16(a[mf][1], b1, acc[mf][nf], 0, 0, 0);
        acc[mf][nf] = __builtin_amdgcn_mfma_f32_16x16x32_bf16(a[mf][0], b2, acc[mf][nf], 0, 0, 0);
      }
    }
    if (more) SPLITB();  // VALU; overlaps MFMA tail
    abuf ^= 1;
  }

  // C/D: col = lane&15, row = (lane>>4)*4 + r  [m89-verified]
#pragma unroll
  for (int mf = 0; mf < 4; ++mf)
#pragma unroll
    for (int nf = 0; nf < 8; ++nf)
#pragma unroll
      for (int r = 0; r < 4; ++r) {
        int m = m0 + wm * 64 + mf * 16 + c0 * 4 + r;
        int n = n0 + wn * 128 + nf * 16 + l15;
        outp[((size_t)blockIdx.z * Mrows + m) * 8192 + n] = acc[mf][nf][r];
      }
}

// ---- gates: sums 8 z-partials (+ up to 2 zextra), all-tanh; writes h split triple
// (row-major [256][2048]) + optional ydecT fp32 gather for conv2.
__global__ void k_gates(const float* __restrict__ zpart,
                        const float* __restrict__ zx0, const float* __restrict__ zx1,
                        const float* __restrict__ bias, float* __restrict__ c,
                        unsigned short* __restrict__ Hh, unsigned short* __restrict__ Hm,
                        unsigned short* __restrict__ Hl,
                        float* __restrict__ ydecT, int s) {
  int i = blockIdx.x * 256 + threadIdx.x;
  int b = i >> 11, u = i & 2047;
  float g4[4];
#pragma unroll
  for (int gi = 0; gi < 4; ++gi) {
    int n = u + gi * 2048;
    float v = bias[n];
#pragma unroll
    for (int p = 0; p < 8; ++p) v += zpart[((size_t)p * 256 + b) * 8192 + n];
    if (zx0) v += zx0[(size_t)b * 8192 + n];
    if (zx1) v += zx1[(size_t)b * 8192 + n];
    g4[gi] = tanhf(v);
  }
  float cn = g4[1] * c[i] + g4[0] * g4[2];
  c[i] = cn;
  float h = g4[3] * tanhf(cn);
  unsigned short hh, hm, hl;
  split3(h, hh, hm, hl);
  Hh[i] = hh; Hm[i] = hm; Hl[i] = hl;
  if (ydecT) ydecT[(size_t)(u & 511) * 4096 + b * 16 + ((u >> 9) << 2) + s] = h;
}

// ---- IN+lrelu after conv1 (sums 4 kgf partials), writes steps split triple
// rows m = w*256+b, cols k = hh*512+d  ([1024][2048] row-major)
__global__ void k_inorm1(const float* __restrict__ part, const float* __restrict__ gamma,
                         const float* __restrict__ beta,
                         unsigned short* __restrict__ Sh, unsigned short* __restrict__ Sm,
                         unsigned short* __restrict__ Sl) {
  int d = blockIdx.y * 256 + threadIdx.x;  // 0..511
  int b = blockIdx.x;
  float v[16], s = 0.f, s2 = 0.f;
#pragma unroll
  for (int p = 0; p < 16; ++p) {
    float xv = 0.f;
#pragma unroll
    for (int q = 0; q < 4; ++q) xv += part[((size_t)q * 4096 + b * 16 + p) * 512 + d];
    v[p] = xv; s += xv; s2 += xv * xv;
  }
  float mean = s * (1.f / 16.f);
  float var = s2 * (1.f / 16.f) - mean * mean;
  float sc = gamma[d] * rsqrtf(var + EPSN);
  float bt = beta[d];
#pragma unroll
  for (int p = 0; p < 16; ++p) {
    int hh = p >> 2, w = p & 3;
    float xn = (v[p] - mean) * sc + bt;
    xn = xn >= 0.f ? xn : 0.2f * xn;
    size_t a = (size_t)(w * 256 + b) * 2048 + hh * 512 + d;
    unsigned short th, tm, tl;
    split3(xn, th, tm, tl);
    Sh[a] = th; Sm[a] = tm; Sl[a] = tl;
  }
}

// ---- IN+lrelu after conv2 (sums 2 kgf partials), writes final out [B,4,4,1024]
__global__ void k_inorm2(const float* __restrict__ part, const float* __restrict__ gamma,
                         const float* __restrict__ beta, float* __restrict__ out) {
  int o = blockIdx.y * 256 + threadIdx.x;  // 0..1023
  int b = blockIdx.x;
  float v[16], s = 0.f, s2 = 0.f;
#pragma unroll
  for (int p = 0; p < 16; ++p) {
    float xv = part[((size_t)(b * 16 + p)) * 1024 + o] +
               part[((size_t)(4096 + b * 16 + p)) * 1024 + o];
    v[p] = xv; s += xv; s2 += xv * xv;
  }
  float mean = s * (1.f / 16.f);
  float var = s2 * (1.f / 16.f) - mean * mean;
  float sc = gamma[o] * rsqrtf(var + EPSN);
  float bt = beta[o];
#pragma unroll
  for (int p = 0; p < 16; ++p) {
    float xn = (v[p] - mean) * sc + bt;
    xn = xn >= 0.f ? xn : 0.2f * xn;
    out[((size_t)(b * 16 + p)) * 1024 + o] = xn;
  }
}

extern "C" void kernel_launch(void* const* d_in, const int* in_sizes, int n_in,
                              void* d_out, int out_size, void* d_ws, size_t ws_size,
                              hipStream_t stream) {
  (void)in_sizes; (void)n_in; (void)out_size;
  const float* x     = (const float*)d_in[0];
  const float* w1    = (const float*)d_in[1];
  const float* g1    = (const float*)d_in[2];
  const float* b1    = (const float*)d_in[3];
  const float* enc_k = (const float*)d_in[4];
  const float* enc_r = (const float*)d_in[5];
  const float* enc_b = (const float*)d_in[6];
  const float* dec_k = (const float*)d_in[7];
  const float* dec_r = (const float*)d_in[8];
  const float* dec_b = (const float*)d_in[9];
  const float* w2    = (const float*)d_in[10];
  const float* g2    = (const float*)d_in[11];
  const float* b2    = (const float*)d_in[12];
  float* out = (float*)d_out;

  if (ws_size < 176160768ULL) return;  // 168 MiB known-good bound

  // Manual layout, 166 MiB total (see r10):
  char* base = (char*)d_ws;
  float* zpart = (float*)base;                       // [0,64Mi) 8 cell partials / conv partials
  float* ZX    = (float*)(base + (64ull << 20));     // [64,128Mi) 2 partials [1024][8192]
  char*  xreg  = base + (128ull << 20);              // [128,144Mi) xT -> ydecT+h1s+h2s
  float* xT    = (float*)xreg;
  float* ydecT = (float*)xreg;
  unsigned short* h1s = (unsigned short*)(xreg + (8ull << 20));
  unsigned short* h2s = (unsigned short*)(xreg + (11ull << 20));
  unsigned short* st3 = (unsigned short*)(base + (144ull << 20));
  unsigned short* y0s = (unsigned short*)(base + (156ull << 20));
  unsigned short* y1s = (unsigned short*)(base + (159ull << 20));
  float* c1 = (float*)(base + (162ull << 20));
  float* c2 = (float*)(base + (164ull << 20));

  const size_t SP = 1024ull * 2048;   // steps split stride
  const size_t HP = 256ull * 2048;    // h split stride
  unsigned short *sth = st3, *stm = st3 + SP, *stl = st3 + 2 * SP;
  unsigned short *h1h = h1s, *h1m = h1s + HP, *h1l = h1s + 2 * HP;
  unsigned short *h2h = h2s, *h2m = h2s + HP, *h2l = h2s + 2 * HP;
  unsigned short* ys[2] = {y0s, y1s};

  // conv1 (fp32 path) — uses xT region, so h1s/h2s memsets come AFTER
  kTx<<<dim3(128, 32), dim3(32, 8), 0, stream>>>(x, xT, 4096, 1024);
  kgf<<<dim3(4, 32, 4), 256, 0, stream>>>(xT, 4096, xT, 4096, w1, w1, 512,
                                          1024, 512, 4096, 256, zpart);
  k_inorm1<<<dim3(256, 2), 256, 0, stream>>>(zpart, g1, b1, sth, stm, stl);

  hipMemsetAsync(h1s, 0, 3 * HP * 2, stream);
  hipMemsetAsync(h2s, 0, 3 * HP * 2, stream);
  hipMemsetAsync(c1, 0, HP * 4, stream);
  hipMemsetAsync(c2, 0, HP * 4, stream);

  // ZX = steps @ enc_k (all 4 timesteps): [1024 x 2048] @ [2048][8192], 2 partials
  kgm<<<dim3(32, 4, 2), 512, 0, stream>>>(sth, stm, stl, sth, stm, stl,
                                          enc_k, enc_k, 1024, 1024, ZX);

  // encoder: 4 steps x 2 shared-weight layers
  for (int t = 0; t < 4; ++t) {
    kgm<<<dim3(32, 1, 8), 512, 0, stream>>>(h1h, h1m, h1l, h1h, h1m, h1l,
                                            enc_r, enc_r, 256, 256, zpart);
    k_gates<<<2048, 256, 0, stream>>>(zpart, ZX + (size_t)t * 256 * 8192,
                                      ZX + (size_t)(1024 + t * 256) * 8192, enc_b, c1,
                                      h1h, h1m, h1l, nullptr, 0);
    kgm<<<dim3(32, 1, 8), 512, 0, stream>>>(h1h, h1m, h1l, h2h, h2m, h2l,
                                            enc_k, enc_r, 256, 512, zpart);
    k_gates<<<2048, 256, 0, stream>>>(zpart, nullptr, nullptr, enc_b, c2,
                                      h2h, h2m, h2l, nullptr, 0);
  }
  // decoder
  for (int s = 0; s < 4; ++s) {
    const unsigned short *xh, *xm, *xl, *ph, *pm, *pl;
    if (s == 0) {
      xh = sth + 768 * 2048; xm = stm + 768 * 2048; xl = stl + 768 * 2048;
      ph = h2h; pm = h2m; pl = h2l;
    } else {
      unsigned short* pr = ys[(s - 1) & 1];
      xh = pr; xm = pr + HP; xl = pr + 2 * HP;
      ph = pr; pm = pr + HP; pl = pr + 2 * HP;
    }
    kgm<<<dim3(32, 1, 8), 512, 0, stream>>>(xh, xm, xl, h1h, h1m, h1l,
                                            dec_k, dec_r, 256, 512, zpart);
    k_gates<<<2048, 256, 0, stream>>>(zpart, nullptr, nullptr, dec_b, c1,
                                      h1h, h1m, h1l, nullptr, 0);
    kgm<<<dim3(32, 1, 8), 512, 0, stream>>>(h1h, h1m, h1l, ph, pm, pl,
                                            dec_k, dec_r, 256, 512, zpart);
    unsigned short* cur = ys[s & 1];
    k_gates<<<2048, 256, 0, stream>>>(zpart, nullptr, nullptr, dec_b, c2,
                                      cur, cur + HP, cur + 2 * HP, ydecT, s);
  }

  // conv2 (fp32 path): gathered y [4096 x 512] @ w2 -> zpart[2][4096][1024]
  kgf<<<dim3(8, 32, 2), 256, 0, stream>>>(ydecT, 4096, ydecT, 4096, w2, w2, 1024,
                                          512, 1024, 4096, 256, zpart);
  k_inorm2<<<dim3(256, 4), 256, 0, stream>>>(zpart, g2, b2, out);
}

// Round 12
// 1399.620 us; speedup vs baseline: 1.5013x; 1.2379x over previous
//
#include <hip/hip_runtime.h>

#define EPSN 1e-6f

typedef __attribute__((ext_vector_type(4))) float f32x4;
typedef __attribute__((ext_vector_type(8))) __bf16 bf16x8;
typedef __attribute__((ext_vector_type(8))) unsigned short us8;

__device__ __forceinline__ void async16(const void* g, void* l) {
  __builtin_amdgcn_global_load_lds(
      (const __attribute__((address_space(1))) unsigned int*)g,
      (__attribute__((address_space(3))) unsigned int*)l, 16, 0, 0);
}

// 2-level bf16 split: v ~= h + m with residual <= 2^-18 rel
__device__ __forceinline__ void split2(float v, unsigned short& h, unsigned short& m) {
  __bf16 a = (__bf16)v;  float fa = (float)a;
  __bf16 b = (__bf16)(v - fa);
  h = __builtin_bit_cast(unsigned short, a);
  m = __builtin_bit_cast(unsigned short, b);
}

// ---- transpose: out[c][r] = in[r][c], in [R][C] fp32 (for conv1 A-side)
__global__ void kTx(const float* __restrict__ in, float* __restrict__ out, int R, int C) {
  __shared__ float t[32][33];
  int r0 = blockIdx.x * 32, c0 = blockIdx.y * 32;
  int tx = threadIdx.x, ty = threadIdx.y;  // (32,8)
#pragma unroll
  for (int j = 0; j < 4; ++j)
    t[ty + j * 8][tx] = in[(size_t)(r0 + ty + j * 8) * C + c0 + tx];
  __syncthreads();
#pragma unroll
  for (int j = 0; j < 4; ++j)
    out[(size_t)(c0 + ty + j * 8) * R + r0 + tx] = t[tx][ty + j * 8];
}

// ==== fp32 vector GEMM (proven) — conv1/conv2 only ====
__global__ __launch_bounds__(256, 2) void kgf(
    const float* __restrict__ A0, int lda0, const float* __restrict__ A1, int lda1,
    const float* __restrict__ B0, const float* __restrict__ B1, int ldb,
    int splitK, int N, int M, int kchunk, float* __restrict__ outp) {
  __shared__ float lsA[2][16 * 128];
  __shared__ float lsB[2][16 * 128];
  const int tid = threadIdx.x;
  const int n0 = blockIdx.x * 128, m0 = blockIdx.y * 128;
  const int kbase = blockIdx.z * kchunk;
  const float* A; int lda; const float* B; int koff;
  if (kbase < splitK) { A = A0; lda = lda0; B = B0; koff = kbase; }
  else                { A = A1; lda = lda1; B = B1; koff = kbase - splitK; }
  const int nt = kchunk >> 4;
  const float* asrc[2]; const float* bsrc[2];
#pragma unroll
  for (int j = 0; j < 2; ++j) {
    int idx = j * 256 + tid;
    int r = idx >> 5, c4 = (idx & 31) * 4;
    asrc[j] = A + (size_t)(koff + r) * lda + m0 + c4;
    bsrc[j] = B + (size_t)(koff + r) * ldb + n0 + c4;
  }
  const size_t astep = (size_t)16 * lda, bstep = (size_t)16 * ldb;
  const int wbase = (tid & ~63) * 16;
  auto STAGE = [&](int buf) {
#pragma unroll
    for (int j = 0; j < 2; ++j) {
      async16(asrc[j], (char*)&lsA[buf][0] + j * 4096 + wbase);
      async16(bsrc[j], (char*)&lsB[buf][0] + j * 4096 + wbase);
      asrc[j] += astep; bsrc[j] += bstep;
    }
  };
  const int mg = tid >> 4, ng = tid & 15;
  f32x4 acc[8][2];
#pragma unroll
  for (int i = 0; i < 8; ++i) { acc[i][0] = (f32x4){0,0,0,0}; acc[i][1] = (f32x4){0,0,0,0}; }
  STAGE(0);
  __syncthreads();
  int buf = 0;
  for (int t = 0; t < nt; ++t) {
    if (t + 1 < nt) STAGE(buf ^ 1);
#pragma unroll
    for (int k = 0; k < 16; ++k) {
      f32x4 a0 = *(const f32x4*)&lsA[buf][k * 128 + mg * 8];
      f32x4 a1 = *(const f32x4*)&lsA[buf][k * 128 + mg * 8 + 4];
      f32x4 b0 = *(const f32x4*)&lsB[buf][k * 128 + ng * 4];
      f32x4 b1 = *(const f32x4*)&lsB[buf][k * 128 + ng * 4 + 64];
#pragma unroll
      for (int i = 0; i < 8; ++i) {
        float av = (i < 4) ? a0[i] : a1[i - 4];
        acc[i][0] += av * b0; acc[i][1] += av * b1;
      }
    }
    __syncthreads();
    buf ^= 1;
  }
  float* o = outp + ((size_t)blockIdx.z * M + m0 + mg * 8) * N + n0;
#pragma unroll
  for (int i = 0; i < 8; ++i) {
    *(f32x4*)&o[(size_t)i * N + ng * 4] = acc[i][0];
    *(f32x4*)&o[(size_t)i * N + ng * 4 + 64] = acc[i][1];
  }
}

// ==== MFMA emulated-fp32 GEMM (4-term 2-way bf16 split: hh+hm+mh+mm) ====
// BM=BN=256, BK=32, 512 threads / 8 waves, wave tile 64x128, 16x16x32 MFMA.
// A: pre-split bf16 (h,m) [m][2048] row-major; kbase<2048 -> (Ah0,Am0)/B0 else (Ah1,..)/B1.
// B fp32 [k][8192]. out[bz][m][n], Mrows rows per partial. kchunk must not straddle 2048.
// A via global_load_lds into double-buffered lsA (src slot-XOR pre-swizzled, linear dest);
// B reg-loaded + split2 + conflict-free ds_write_b128 (single lsB).
__global__ __launch_bounds__(512, 1) void kgm(
    const unsigned short* __restrict__ Ah0, const unsigned short* __restrict__ Am0,
    const unsigned short* __restrict__ Ah1, const unsigned short* __restrict__ Am1,
    const float* __restrict__ B0, const float* __restrict__ B1,
    int Mrows, int kchunk, float* __restrict__ outp) {
  __shared__ unsigned short lsA[2][2 * 256 * 32];  // 2 x 32KB, [split][m][32k], slot-XOR swz
  __shared__ unsigned short lsB[2 * 4 * 256 * 8];  // 32KB, [split][kq][n][8k], linear
  const int tid = threadIdx.x, lane = tid & 63, wid = tid >> 6;
  const int n0 = blockIdx.x * 256, m0 = blockIdx.y * 256;
  const int kbase = blockIdx.z * kchunk;

  const unsigned short *Ah, *Am; const float* B; int koff;
  if (kbase < 2048) { Ah = Ah0; Am = Am0; B = B0; koff = kbase; }
  else              { Ah = Ah1; Am = Am1; B = B1; koff = kbase - 2048; }
  const int nt = kchunk >> 5;

  // --- A: 2048 16B-chunks, 4/thread. idx=j*512+tid -> split=idx>>10,
  // row=(idx&1023)>>2, slot=idx&3. Dest linear idx*16B (wave-uniform base + lane*16);
  // SOURCE pre-swizzled slot^((row>>1)&3); read applies the same XOR.
  const unsigned short* asrc[4];
  int adst[4];
#pragma unroll
  for (int j = 0; j < 4; ++j) {
    int idx = j * 512 + tid;
    int s = idx >> 10, rem = idx & 1023, row = rem >> 2, slot = idx & 3;
    const unsigned short* base = (s == 0) ? Ah : Am;
    asrc[j] = base + (size_t)(m0 + row) * 2048 + koff + ((slot ^ ((row >> 1) & 3)) << 3);
    adst[j] = (j * 512 + (tid & ~63)) * 16;  // wave-uniform byte base; HW adds lane*16
  }
  auto STAGEA = [&](int buf) {
#pragma unroll
    for (int j = 0; j < 4; ++j) {
      async16(asrc[j], (char*)&lsA[buf][0] + adst[j]);
      asrc[j] += 32;
    }
  };

  // --- B: thread owns k rows kq*8..+7 (kq=tid>>7), n in {nn, nn+128} (nn=tid&127).
  const int kq = tid >> 7, nn = tid & 127;
  const float* bptr = B + (size_t)(koff + kq * 8) * 8192 + n0 + nn;
  const int bo0 = kq * 2048 + nn * 8;
  const int bo1 = kq * 2048 + (nn + 128) * 8;
  float bwa[8], bwb[8];
  us8 bs[4];  // h_a, m_a, h_b, m_b
  auto LOADB = [&]() {
#pragma unroll
    for (int r = 0; r < 8; ++r) {
      bwa[r] = bptr[(size_t)r * 8192];
      bwb[r] = bptr[(size_t)r * 8192 + 128];
    }
    bptr += (size_t)32 * 8192;
  };
  auto SPLITB = [&]() {
#pragma unroll
    for (int r = 0; r < 8; ++r) {
      unsigned short h, m;
      split2(bwa[r], h, m);
      bs[0][r] = h; bs[1][r] = m;
      split2(bwb[r], h, m);
      bs[2][r] = h; bs[3][r] = m;
    }
  };
  auto WRITEB = [&]() {
    *(us8*)&lsB[bo0] = bs[0];
    *(us8*)&lsB[8192 + bo0] = bs[1];
    *(us8*)&lsB[bo1] = bs[2];
    *(us8*)&lsB[8192 + bo1] = bs[3];
  };

  const int c0 = lane >> 4, l15 = lane & 15;
  const int wm = wid >> 1, wn = wid & 1;  // wave tile: m 64-block wm, n 128-block wn
  f32x4 acc[4][8];
#pragma unroll
  for (int i = 0; i < 4; ++i)
#pragma unroll
    for (int j = 0; j < 8; ++j) acc[i][j] = (f32x4){0, 0, 0, 0};

  STAGEA(0);
  LOADB();
  SPLITB();
  int abuf = 0;
  for (int t = 0; t < nt; ++t) {
    __syncthreads();  // [1] prev compute done (lsB + lsA[abuf^1] free)
    WRITEB();
    __syncthreads();  // [2] lsB ready; asyncA(t) drained (barrier implies vmcnt(0))
    bool more = (t + 1 < nt);
    if (more) {
      STAGEA(abuf ^ 1);  // A(t+1): DMA runs during compute, drained at next barrier
      LOADB();           // B(t+1) into regs; latency hidden under MFMA
    }
    bf16x8 a[4][2];
#pragma unroll
    for (int mf = 0; mf < 4; ++mf) {
      int m = wm * 64 + mf * 16 + l15;
      int ro = m * 32 + ((c0 ^ ((m >> 1) & 3)) << 3);
      a[mf][0] = *(const bf16x8*)&lsA[abuf][ro];
      a[mf][1] = *(const bf16x8*)&lsA[abuf][8192 + ro];
    }
#pragma unroll
    for (int nf = 0; nf < 8; ++nf) {
      int ro = c0 * 2048 + (wn * 128 + nf * 16 + l15) * 8;
      bf16x8 b0 = *(const bf16x8*)&lsB[ro];
      bf16x8 b1 = *(const bf16x8*)&lsB[8192 + ro];
#pragma unroll
      for (int mf = 0; mf < 4; ++mf) {
        acc[mf][nf] = __builtin_amdgcn_mfma_f32_16x16x32_bf16(a[mf][0], b0, acc[mf][nf], 0, 0, 0);
        acc[mf][nf] = __builtin_amdgcn_mfma_f32_16x16x32_bf16(a[mf][1], b0, acc[mf][nf], 0, 0, 0);
        acc[mf][nf] = __builtin_amdgcn_mfma_f32_16x16x32_bf16(a[mf][0], b1, acc[mf][nf], 0, 0, 0);
        acc[mf][nf] = __builtin_amdgcn_mfma_f32_16x16x32_bf16(a[mf][1], b1, acc[mf][nf], 0, 0, 0);
      }
    }
    if (more) SPLITB();  // VALU; overlaps MFMA tail
    abuf ^= 1;
  }

  // C/D: col = lane&15, row = (lane>>4)*4 + r  [m89-verified]
#pragma unroll
  for (int mf = 0; mf < 4; ++mf)
#pragma unroll
    for (int nf = 0; nf < 8; ++nf)
#pragma unroll
      for (int r = 0; r < 4; ++r) {
        int m = m0 + wm * 64 + mf * 16 + c0 * 4 + r;
        int n = n0 + wn * 128 + nf * 16 + l15;
        outp[((size_t)blockIdx.z * Mrows + m) * 8192 + n] = acc[mf][nf][r];
      }
}

// ---- gates: sums 8 z-partials (+ up to 2 zextra), all-tanh; writes h split pair
// (row-major [256][2048]) + optional ydecT fp32 gather for conv2.
__global__ void k_gates(const float* __restrict__ zpart,
                        const float* __restrict__ zx0, const float* __restrict__ zx1,
                        const float* __restrict__ bias, float* __restrict__ c,
                        unsigned short* __restrict__ Hh, unsigned short* __restrict__ Hm,
                        float* __restrict__ ydecT, int s) {
  int i = blockIdx.x * 256 + threadIdx.x;
  int b = i >> 11, u = i & 2047;
  float g4[4];
#pragma unroll
  for (int gi = 0; gi < 4; ++gi) {
    int n = u + gi * 2048;
    float v = bias[n];
#pragma unroll
    for (int p = 0; p < 8; ++p) v += zpart[((size_t)p * 256 + b) * 8192 + n];
    if (zx0) v += zx0[(size_t)b * 8192 + n];
    if (zx1) v += zx1[(size_t)b * 8192 + n];
    g4[gi] = tanhf(v);
  }
  float cn = g4[1] * c[i] + g4[0] * g4[2];
  c[i] = cn;
  float h = g4[3] * tanhf(cn);
  unsigned short hh, hm;
  split2(h, hh, hm);
  Hh[i] = hh; Hm[i] = hm;
  if (ydecT) ydecT[(size_t)(u & 511) * 4096 + b * 16 + ((u >> 9) << 2) + s] = h;
}

// ---- IN+lrelu after conv1 (sums 4 kgf partials), writes steps split pair
// rows m = w*256+b, cols k = hh*512+d  ([1024][2048] row-major)
__global__ void k_inorm1(const float* __restrict__ part, const float* __restrict__ gamma,
                         const float* __restrict__ beta,
                         unsigned short* __restrict__ Sh, unsigned short* __restrict__ Sm) {
  int d = blockIdx.y * 256 + threadIdx.x;  // 0..511
  int b = blockIdx.x;
  float v[16], s = 0.f, s2 = 0.f;
#pragma unroll
  for (int p = 0; p < 16; ++p) {
    float xv = 0.f;
#pragma unroll
    for (int q = 0; q < 4; ++q) xv += part[((size_t)q * 4096 + b * 16 + p) * 512 + d];
    v[p] = xv; s += xv; s2 += xv * xv;
  }
  float mean = s * (1.f / 16.f);
  float var = s2 * (1.f / 16.f) - mean * mean;
  float sc = gamma[d] * rsqrtf(var + EPSN);
  float bt = beta[d];
#pragma unroll
  for (int p = 0; p < 16; ++p) {
    int hh = p >> 2, w = p & 3;
    float xn = (v[p] - mean) * sc + bt;
    xn = xn >= 0.f ? xn : 0.2f * xn;
    size_t a = (size_t)(w * 256 + b) * 2048 + hh * 512 + d;
    unsigned short th, tm;
    split2(xn, th, tm);
    Sh[a] = th; Sm[a] = tm;
  }
}

// ---- IN+lrelu after conv2 (sums 2 kgf partials), writes final out [B,4,4,1024]
__global__ void k_inorm2(const float* __restrict__ part, const float* __restrict__ gamma,
                         const float* __restrict__ beta, float* __restrict__ out) {
  int o = blockIdx.y * 256 + threadIdx.x;  // 0..1023
  int b = blockIdx.x;
  float v[16], s = 0.f, s2 = 0.f;
#pragma unroll
  for (int p = 0; p < 16; ++p) {
    float xv = part[((size_t)(b * 16 + p)) * 1024 + o] +
               part[((size_t)(4096 + b * 16 + p)) * 1024 + o];
    v[p] = xv; s += xv; s2 += xv * xv;
  }
  float mean = s * (1.f / 16.f);
  float var = s2 * (1.f / 16.f) - mean * mean;
  float sc = gamma[o] * rsqrtf(var + EPSN);
  float bt = beta[o];
#pragma unroll
  for (int p = 0; p < 16; ++p) {
    float xn = (v[p] - mean) * sc + bt;
    xn = xn >= 0.f ? xn : 0.2f * xn;
    out[((size_t)(b * 16 + p)) * 1024 + o] = xn;
  }
}

extern "C" void kernel_launch(void* const* d_in, const int* in_sizes, int n_in,
                              void* d_out, int out_size, void* d_ws, size_t ws_size,
                              hipStream_t stream) {
  (void)in_sizes; (void)n_in; (void)out_size;
  const float* x     = (const float*)d_in[0];
  const float* w1    = (const float*)d_in[1];
  const float* g1    = (const float*)d_in[2];
  const float* b1    = (const float*)d_in[3];
  const float* enc_k = (const float*)d_in[4];
  const float* enc_r = (const float*)d_in[5];
  const float* enc_b = (const float*)d_in[6];
  const float* dec_k = (const float*)d_in[7];
  const float* dec_r = (const float*)d_in[8];
  const float* dec_b = (const float*)d_in[9];
  const float* w2    = (const float*)d_in[10];
  const float* g2    = (const float*)d_in[11];
  const float* b2    = (const float*)d_in[12];
  float* out = (float*)d_out;

  if (ws_size < 176160768ULL) return;  // 168 MiB known-good bound

  // Manual layout (see r10/r11); split pairs now (h,m):
  char* base = (char*)d_ws;
  float* zpart = (float*)base;                       // [0,64Mi) 8 cell partials / conv partials
  float* ZX    = (float*)(base + (64ull << 20));     // [64,128Mi) 2 partials [1024][8192]
  char*  xreg  = base + (128ull << 20);              // [128,144Mi) xT -> ydecT+h1s+h2s
  float* xT    = (float*)xreg;
  float* ydecT = (float*)xreg;
  unsigned short* h1s = (unsigned short*)(xreg + (8ull << 20));
  unsigned short* h2s = (unsigned short*)(xreg + (11ull << 20));
  unsigned short* st2 = (unsigned short*)(base + (144ull << 20));
  unsigned short* y0s = (unsigned short*)(base + (156ull << 20));
  unsigned short* y1s = (unsigned short*)(base + (159ull << 20));
  float* c1 = (float*)(base + (162ull << 20));
  float* c2 = (float*)(base + (164ull << 20));

  const size_t SP = 1024ull * 2048;   // steps split stride
  const size_t HP = 256ull * 2048;    // h split stride
  unsigned short *sth = st2, *stm = st2 + SP;
  unsigned short *h1h = h1s, *h1m = h1s + HP;
  unsigned short *h2h = h2s, *h2m = h2s + HP;
  unsigned short* ys[2] = {y0s, y1s};

  // conv1 (fp32 path) — uses xT region, so h1s/h2s memsets come AFTER
  kTx<<<dim3(128, 32), dim3(32, 8), 0, stream>>>(x, xT, 4096, 1024);
  kgf<<<dim3(4, 32, 4), 256, 0, stream>>>(xT, 4096, xT, 4096, w1, w1, 512,
                                          1024, 512, 4096, 256, zpart);
  k_inorm1<<<dim3(256, 2), 256, 0, stream>>>(zpart, g1, b1, sth, stm);

  hipMemsetAsync(h1s, 0, 2 * HP * 2, stream);
  hipMemsetAsync(h2s, 0, 2 * HP * 2, stream);
  hipMemsetAsync(c1, 0, HP * 4, stream);
  hipMemsetAsync(c2, 0, HP * 4, stream);

  // ZX = steps @ enc_k (all 4 timesteps): [1024 x 2048] @ [2048][8192], 2 partials
  kgm<<<dim3(32, 4, 2), 512, 0, stream>>>(sth, stm, sth, stm,
                                          enc_k, enc_k, 1024, 1024, ZX);

  // encoder: 4 steps x 2 shared-weight layers
  for (int t = 0; t < 4; ++t) {
    kgm<<<dim3(32, 1, 8), 512, 0, stream>>>(h1h, h1m, h1h, h1m,
                                            enc_r, enc_r, 256, 256, zpart);
    k_gates<<<2048, 256, 0, stream>>>(zpart, ZX + (size_t)t * 256 * 8192,
                                      ZX + (size_t)(1024 + t * 256) * 8192, enc_b, c1,
                                      h1h, h1m, nullptr, 0);
    kgm<<<dim3(32, 1, 8), 512, 0, stream>>>(h1h, h1m, h2h, h2m,
                                            enc_k, enc_r, 256, 512, zpart);
    k_gates<<<2048, 256, 0, stream>>>(zpart, nullptr, nullptr, enc_b, c2,
                                      h2h, h2m, nullptr, 0);
  }
  // decoder
  for (int s = 0; s < 4; ++s) {
    const unsigned short *xh, *xm, *ph, *pm;
    if (s == 0) {
      xh = sth + 768 * 2048; xm = stm + 768 * 2048;
      ph = h2h; pm = h2m;
    } else {
      unsigned short* pr = ys[(s - 1) & 1];
      xh = pr; xm = pr + HP;
      ph = pr; pm = pr + HP;
    }
    kgm<<<dim3(32, 1, 8), 512, 0, stream>>>(xh, xm, h1h, h1m,
                                            dec_k, dec_r, 256, 512, zpart);
    k_gates<<<2048, 256, 0, stream>>>(zpart, nullptr, nullptr, dec_b, c1,
                                      h1h, h1m, nullptr, 0);
    kgm<<<dim3(32, 1, 8), 512, 0, stream>>>(h1h, h1m, ph, pm,
                                            dec_k, dec_r, 256, 512, zpart);
    unsigned short* cur = ys[s & 1];
    k_gates<<<2048, 256, 0, stream>>>(zpart, nullptr, nullptr, dec_b, c2,
                                      cur, cur + HP, ydecT, s);
  }

  // conv2 (fp32 path): gathered y [4096 x 512] @ w2 -> zpart[2][4096][1024]
  kgf<<<dim3(8, 32, 2), 256, 0, stream>>>(ydecT, 4096, ydecT, 4096, w2, w2, 1024,
                                          512, 1024, 4096, 256, zpart);
  k_inorm2<<<dim3(256, 4), 256, 0, stream>>>(zpart, g2, b2, out);
}